// Round 9
// baseline (267.055 us; speedup 1.0000x reference)
//
#include <hip/hip_runtime.h>
#include <math.h>

// Problem constants (from reference): T=131072, D_IN=1024, NE=64, top_k=2
constexpr int T_TOKENS = 131072;
constexpr int D        = 1024;
constexpr int NEXP     = 64;

constexpr int BM = 256;  // tokens per block
constexpr int BK = 32;   // K-slice per LDS buffer (double-buffered)
constexpr int NTHREADS = 256;

// np ref = OpenBLAS sgemm, SKYLAKEX target (verified R7): K=1024 split into
// panels 320+320+192+192; per (t,e) each panel is a single ascending-k fp32
// FMA chain from 0; C folded sequentially: (((P1+P2)+P3)+P4), folds rounded
// separately at k = 320, 640, 832, 1024 (all multiples of BK=32).
//
// 8x8 register tile per thread (tx=tid&7 -> experts n0=tx*8, ty=tid>>3 ->
// tokens m0=ty*8). Double-buffered LDS staging: issue next chunk's global
// loads -> compute current buffer -> ds_write other buffer -> ONE barrier.
// Removes the per-k0 vmcnt(0)+barrier drain that cost ~95us in R8.
__global__ __launch_bounds__(NTHREADS, 2)
void topk_router_kernel(const float* __restrict__ x,
                        const float* __restrict__ W,
                        float* __restrict__ out)
{
    __shared__ float Xs[2][BK][BM];   // 2 x 32 x 256 x 4B = 64 KB
    __shared__ float Ws[2][BK][NEXP]; // 2 x 32 x 64 x 4B  = 16 KB

    const int tid = threadIdx.x;
    const long t0 = (long)blockIdx.x * BM;

    const int tx = tid & 7;
    const int ty = tid >> 3;
    const int n0 = tx * 8;
    const int m0 = ty * 8;

    float accP[8][8];   // current-panel accumulator (FMA chain)
    float accT[8][8];   // folded total
#pragma unroll
    for (int i = 0; i < 8; ++i)
#pragma unroll
        for (int j = 0; j < 8; ++j) { accP[i][j] = 0.0f; accT[i][j] = 0.0f; }

    // staging: x -> thread owns token `tid` (32 floats/chunk);
    //          W -> row tid&63, k-octet tid>>6 (8 floats/chunk)
    const float* xrow = x + (t0 + tid) * (long)D;
    const int wr = tid & 63;
    const int wc = tid >> 6;            // 0..3
    const float* wrow = W + (long)wr * D;

    float4 xv[8];   // next x chunk (32 floats)
    float4 wv[2];   // next W chunk (8 floats)

    // ---- prologue: load chunk 0, write buffer 0 ----
#pragma unroll
    for (int u = 0; u < 8; ++u)
        xv[u] = *reinterpret_cast<const float4*>(xrow + u * 4);
#pragma unroll
    for (int q = 0; q < 2; ++q)
        wv[q] = *reinterpret_cast<const float4*>(wrow + wc * 8 + q * 4);
#pragma unroll
    for (int u = 0; u < 8; ++u) {
        Xs[0][u * 4 + 0][tid] = xv[u].x;
        Xs[0][u * 4 + 1][tid] = xv[u].y;
        Xs[0][u * 4 + 2][tid] = xv[u].z;
        Xs[0][u * 4 + 3][tid] = xv[u].w;
    }
#pragma unroll
    for (int q = 0; q < 2; ++q) {
        Ws[0][wc * 8 + q * 4 + 0][wr] = wv[q].x;
        Ws[0][wc * 8 + q * 4 + 1][wr] = wv[q].y;
        Ws[0][wc * 8 + q * 4 + 2][wr] = wv[q].z;
        Ws[0][wc * 8 + q * 4 + 3][wr] = wv[q].w;
    }
    __syncthreads();

    for (int kc = 0; kc < D; kc += BK) {
        const int p = (kc / BK) & 1;
        const bool more = (kc + BK) < D;

        // issue next chunk's global loads (latency hides under compute)
        if (more) {
#pragma unroll
            for (int u = 0; u < 8; ++u)
                xv[u] = *reinterpret_cast<const float4*>(xrow + kc + BK + u * 4);
#pragma unroll
            for (int q = 0; q < 2; ++q)
                wv[q] = *reinterpret_cast<const float4*>(wrow + kc + BK + wc * 8 + q * 4);
        }

        // ascending k, one fp32 FMA per k per element (BLAS microkernel chain)
#pragma unroll 4
        for (int kk = 0; kk < BK; ++kk) {
            float4 a0 = *reinterpret_cast<const float4*>(&Xs[p][kk][m0]);
            float4 a1 = *reinterpret_cast<const float4*>(&Xs[p][kk][m0 + 4]);
            float4 b0 = *reinterpret_cast<const float4*>(&Ws[p][kk][n0]);
            float4 b1 = *reinterpret_cast<const float4*>(&Ws[p][kk][n0 + 4]);
            const float af[8] = {a0.x, a0.y, a0.z, a0.w, a1.x, a1.y, a1.z, a1.w};
            const float bf[8] = {b0.x, b0.y, b0.z, b0.w, b1.x, b1.y, b1.z, b1.w};
#pragma unroll
            for (int i = 0; i < 8; ++i)
#pragma unroll
                for (int j = 0; j < 8; ++j)
                    accP[i][j] = fmaf(af[i], bf[j], accP[i][j]);
        }

        // write next chunk into the other buffer
        if (more) {
            const int b = p ^ 1;
#pragma unroll
            for (int u = 0; u < 8; ++u) {
                Xs[b][u * 4 + 0][tid] = xv[u].x;
                Xs[b][u * 4 + 1][tid] = xv[u].y;
                Xs[b][u * 4 + 2][tid] = xv[u].z;
                Xs[b][u * 4 + 3][tid] = xv[u].w;
            }
#pragma unroll
            for (int q = 0; q < 2; ++q) {
                Ws[b][wc * 8 + q * 4 + 0][wr] = wv[q].x;
                Ws[b][wc * 8 + q * 4 + 1][wr] = wv[q].y;
                Ws[b][wc * 8 + q * 4 + 2][wr] = wv[q].z;
                Ws[b][wc * 8 + q * 4 + 3][wr] = wv[q].w;
            }
        }
        __syncthreads();

        // OpenBLAS SKYLAKEX K-split of 1024: 320 + 320 + 192 + 192
        const int kend = kc + BK;
        if (kend == 320 || kend == 640 || kend == 832 || kend == 1024) {
#pragma unroll
            for (int i = 0; i < 8; ++i)
#pragma unroll
                for (int j = 0; j < 8; ++j) {
                    accT[i][j] = __fadd_rn(accT[i][j], accP[i][j]);
                    accP[i][j] = 0.0f;
                }
        }
    }

    // Epilogue: per-token top-2 over 64 experts (lower index wins ties).
    // Token m0+i's logits live in the 8 lanes sharing ty, 8 experts per lane.
#pragma unroll
    for (int i = 0; i < 8; ++i) {
        float v1 = accT[i][0]; int i1 = n0;
        float v2 = -INFINITY;  int i2 = 1 << 20;
#pragma unroll
        for (int j = 1; j < 8; ++j) {
            const float v = accT[i][j]; const int e = n0 + j;
            if (v > v1)      { v2 = v1; i2 = i1; v1 = v; i1 = e; }
            else if (v > v2) { v2 = v;  i2 = e; }
        }
        // merge across the 8-lane expert group (xor masks stay within tx bits)
#pragma unroll
        for (int m = 4; m >= 1; m >>= 1) {
            const float ov1 = __shfl_xor(v1, m);
            const int   oi1 = __shfl_xor(i1, m);
            const float ov2 = __shfl_xor(v2, m);
            const int   oi2 = __shfl_xor(i2, m);
            // tie-break: lower index wins on equal value
            const bool aw = (ov1 > v1) || (ov1 == v1 && oi1 < i1);
            const float nv1 = aw ? ov1 : v1; const int ni1 = aw ? oi1 : i1;
            const float c1v = aw ? v1  : ov1; const int c1i = aw ? i1  : oi1;
            const float c2v = aw ? ov2 : v2;  const int c2i = aw ? oi2 : i2;
            const bool bw = (c1v > c2v) || (c1v == c2v && c1i < c2i);
            v1 = nv1; i1 = ni1;
            v2 = bw ? c1v : c2v; i2 = bw ? c1i : c2i;
        }
        if (tx == 0) {
            const long t = t0 + m0 + i;
            const float e  = expf(v2 - v1);   // <= 1
            const float dn = 1.0f + e;
            out[t * 2 + 0] = (float)i1;       // indices stored as float values
            out[t * 2 + 1] = (float)i2;
            out[(long)T_TOKENS * 2 + t * 2 + 0] = 1.0f / dn;
            out[(long)T_TOKENS * 2 + t * 2 + 1] = e / dn;
        }
    }
}

extern "C" void kernel_launch(void* const* d_in, const int* in_sizes, int n_in,
                              void* d_out, int out_size, void* d_ws, size_t ws_size,
                              hipStream_t stream) {
    const float* x = (const float*)d_in[0];
    const float* W = (const float*)d_in[1];
    float* out = (float*)d_out;
    // d_in[2] is top_k (==2), fixed by the problem; k=2 is hardcoded.

    dim3 grid(T_TOKENS / BM);
    dim3 block(NTHREADS);
    topk_router_kernel<<<grid, block, 0, stream>>>(x, W, out);
}

// Round 10
// 220.524 us; speedup vs baseline: 1.2110x; 1.2110x over previous
//
#include <hip/hip_runtime.h>
#include <math.h>

// Problem constants: T=131072, D_IN=1024, NE=64, top_k=2
constexpr int T_TOKENS = 131072;
constexpr int D        = 1024;
constexpr int NSTEPS   = 32;       // K steps of 32
constexpr float EPS_GAP = 1e-3f;   // flag threshold (approx err ~5e-6 RMS)

typedef __attribute__((ext_vector_type(8))) short bf16x8;
typedef __attribute__((ext_vector_type(4))) float f32x4;

__device__ __forceinline__ short bf16_rn(float f) {
    unsigned u = __builtin_bit_cast(unsigned, f);
    return (short)((u + 0x7FFFu + ((u >> 16) & 1u)) >> 16);
}
__device__ __forceinline__ float bf16_f(short s) {
    unsigned u = ((unsigned)(unsigned short)s) << 16;
    return __builtin_bit_cast(float, u);
}

// split 8 fp32 (lo,hi) into two bf16 planes: f ~= p0 + p1
__device__ __forceinline__ void split2(const float4 lo, const float4 hi,
                                       bf16x8& p0, bf16x8& p1) {
    const float f[8] = {lo.x, lo.y, lo.z, lo.w, hi.x, hi.y, hi.z, hi.w};
#pragma unroll
    for (int j = 0; j < 8; ++j) {
        const short h = bf16_rn(f[j]);
        p0[j] = h;
        p1[j] = bf16_rn(f[j] - bf16_f(h));
    }
}

// ---------------- Kernel 1: bf16-split MFMA router (fast path) --------------
// Block: 256 thr = 4 waves; 128 tokens/block. Wave: 32 tokens (2 tiles of 16)
// x 64 experts (4 ctiles of 16). A (x) loaded global->reg, split in-reg.
// W staged per 32-k step into LDS lane-major (double-buffered, 16 KB).
// 3 MFMA passes: x0*w0 + x1*w0 + x0*w1 (missing x1*w1 ~ 2^-18 -> ~5e-6 RMS).
__global__ __launch_bounds__(256, 4)
void router_mfma(const float* __restrict__ x, const float* __restrict__ W,
                 float* __restrict__ out, unsigned* __restrict__ wcnt,
                 unsigned* __restrict__ wlist, unsigned cap)
{
    __shared__ __align__(16) short Bs[2][4][2][64 * 8];  // [buf][ctile][plane][slot*8]

    const int tid = threadIdx.x;
    const int wv  = tid >> 6;
    const int l   = tid & 63;
    const int lg  = l >> 4;       // lane group 0..3 (k-octet for frags)
    const int lr  = l & 15;       // row/col within 16
    const long t0 = (long)blockIdx.x * 128 + wv * 32;

    f32x4 acc[2][4];
#pragma unroll
    for (int a = 0; a < 2; ++a)
#pragma unroll
        for (int c = 0; c < 4; ++c) acc[a][c] = f32x4{0.f, 0.f, 0.f, 0.f};

    // A: lane l covers token row (t0 + a*16 + lr), k-octet lg (8 fp32/step)
    const float* xr0 = x + (t0 + lr) * (long)D + lg * 8;
    const float* xr1 = x + (t0 + 16 + lr) * (long)D + lg * 8;
    // W staging: expert e = l, k-octet g = wv (8 fp32/step)
    const float* wp = W + (long)l * D + wv * 8;
    // B write slot: ctile = l>>4, slot = (l&15) + 16*wv
    const int wslot = (lr + 16 * wv) * 8;
    const int wct   = lg;

    float4 af[2][2], wf[2];
    bf16x8 afr[2][2];   // [tile][plane]

    // ---- prologue: step 0 ----
    af[0][0] = *(const float4*)(xr0);      af[0][1] = *(const float4*)(xr0 + 4);
    af[1][0] = *(const float4*)(xr1);      af[1][1] = *(const float4*)(xr1 + 4);
    wf[0]    = *(const float4*)(wp);       wf[1]    = *(const float4*)(wp + 4);
    split2(af[0][0], af[0][1], afr[0][0], afr[0][1]);
    split2(af[1][0], af[1][1], afr[1][0], afr[1][1]);
    {
        bf16x8 q0, q1; split2(wf[0], wf[1], q0, q1);
        *(bf16x8*)&Bs[0][wct][0][wslot] = q0;
        *(bf16x8*)&Bs[0][wct][1][wslot] = q1;
    }
    __syncthreads();

#pragma unroll 2
    for (int s = 0; s < NSTEPS; ++s) {
        const int buf = s & 1;
        if (s + 1 < NSTEPS) {   // issue next step's global loads
            const int o = (s + 1) * 32;
            af[0][0] = *(const float4*)(xr0 + o); af[0][1] = *(const float4*)(xr0 + o + 4);
            af[1][0] = *(const float4*)(xr1 + o); af[1][1] = *(const float4*)(xr1 + o + 4);
            wf[0]    = *(const float4*)(wp + o);  wf[1]    = *(const float4*)(wp + o + 4);
        }
        // MFMA phase: 8 conflict-free ds_read_b128 + 24 MFMA
#pragma unroll
        for (int c = 0; c < 4; ++c) {
            bf16x8 b0 = *(const bf16x8*)&Bs[buf][c][0][l * 8];
            bf16x8 b1 = *(const bf16x8*)&Bs[buf][c][1][l * 8];
#pragma unroll
            for (int a = 0; a < 2; ++a) {
                acc[a][c] = __builtin_amdgcn_mfma_f32_16x16x32_bf16(afr[a][0], b0, acc[a][c], 0, 0, 0);
                acc[a][c] = __builtin_amdgcn_mfma_f32_16x16x32_bf16(afr[a][1], b0, acc[a][c], 0, 0, 0);
                acc[a][c] = __builtin_amdgcn_mfma_f32_16x16x32_bf16(afr[a][0], b1, acc[a][c], 0, 0, 0);
            }
        }
        if (s + 1 < NSTEPS) {   // convert next A, stage next W
            split2(af[0][0], af[0][1], afr[0][0], afr[0][1]);
            split2(af[1][0], af[1][1], afr[1][0], afr[1][1]);
            bf16x8 q0, q1; split2(wf[0], wf[1], q0, q1);
            *(bf16x8*)&Bs[buf ^ 1][wct][0][wslot] = q0;
            *(bf16x8*)&Bs[buf ^ 1][wct][1][wslot] = q1;
        }
        __syncthreads();
    }

    // ---- epilogue: top-3 per token, provisional write + gap-flag ----
    // C/D: col = lane&15 (expert within ctile), row = (lane>>4)*4 + reg (token)
#pragma unroll
    for (int a = 0; a < 2; ++a)
#pragma unroll
    for (int r = 0; r < 4; ++r) {
        float v1 = acc[a][0][r]; int i1 = lr;
        float v2 = -INFINITY;    int i2 = 1 << 20;
        float v3 = -INFINITY;
#pragma unroll
        for (int c = 1; c < 4; ++c) {
            const float v = acc[a][c][r]; const int e = lr + 16 * c;
            if (v > v1)      { v3 = v2; v2 = v1; i2 = i1; v1 = v; i1 = e; }
            else if (v > v2) { v3 = v2; v2 = v;  i2 = e; }
            else if (v > v3) { v3 = v; }
        }
#pragma unroll
        for (int m = 8; m >= 1; m >>= 1) {
            const float ov1 = __shfl_xor(v1, m);
            const int   oi1 = __shfl_xor(i1, m);
            const float ov2 = __shfl_xor(v2, m);
            const int   oi2 = __shfl_xor(i2, m);
            const float ov3 = __shfl_xor(v3, m);
            // third value of merged lists (values only)
            const bool tv = v1 >= ov1;
            const float x1 = tv ? v1 : ov1, x2 = tv ? v2 : ov2, x3 = tv ? v3 : ov3;
            const float y1 = tv ? ov1 : v1, y2 = tv ? ov2 : v2, y3 = tv ? ov3 : v3;
            const float nv3 = (x2 >= y1) ? fmaxf(x3, y1) : fmaxf(x2, y2);
            (void)y3;
            // exact top-2 merge (R7-verified comparator: lower index wins ties)
            const bool aw = (ov1 > v1) || (ov1 == v1 && oi1 < i1);
            const float nv1 = aw ? ov1 : v1; const int ni1 = aw ? oi1 : i1;
            const float c1v = aw ? v1  : ov1; const int c1i = aw ? i1  : oi1;
            const float c2v = aw ? ov2 : v2;  const int c2i = aw ? oi2 : i2;
            const bool bw = (c1v > c2v) || (c1v == c2v && c1i < c2i);
            v1 = nv1; i1 = ni1;
            v2 = bw ? c1v : c2v; i2 = bw ? c1i : c2i;
            v3 = nv3;
        }
        if (lr == 0) {
            const long t = t0 + a * 16 + lg * 4 + r;
            const float e  = expf(v2 - v1);
            const float dn = 1.0f + e;
            out[t * 2 + 0] = (float)i1;
            out[t * 2 + 1] = (float)i2;
            out[(long)T_TOKENS * 2 + t * 2 + 0] = 1.0f / dn;
            out[(long)T_TOKENS * 2 + t * 2 + 1] = e / dn;
            if ((v1 - v2 < EPS_GAP || v2 - v3 < EPS_GAP) && wcnt) {
                const unsigned p = atomicAdd(wcnt, 1u);
                if (p < cap) wlist[p] = (unsigned)t;
            }
        }
    }
}

// ---------------- Kernel 2: exact-chain fixup for flagged tokens ------------
// One wave per token; lane = expert. Exact OpenBLAS-SKYLAKEX chain (verified
// R7): ascending-k fp32 FMA per panel, folds at k=320,640,832,1024.
__global__ __launch_bounds__(256)
void router_fixup(const float* __restrict__ x, const float* __restrict__ W,
                  float* __restrict__ out, const unsigned* __restrict__ wcnt,
                  const unsigned* __restrict__ wlist, unsigned cap)
{
    if (!wcnt) return;
    unsigned cnt = wcnt[0]; if (cnt > cap) cnt = cap;
    const int l = threadIdx.x & 63;
    const int wave = blockIdx.x * (blockDim.x >> 6) + (threadIdx.x >> 6);
    const int nw = gridDim.x * (blockDim.x >> 6);

    for (unsigned it = wave; it < cnt; it += nw) {
        const long t = (long)wlist[it];
        const float* xr = x + t * (long)D;
        const float* wr = W + (long)l * D;
        float accT = 0.f, accP = 0.f;
#pragma unroll 4
        for (int k = 0; k < D; k += 4) {
            const float4 xv = *(const float4*)(xr + k);
            const float4 wv = *(const float4*)(wr + k);
            accP = fmaf(xv.x, wv.x, accP);
            accP = fmaf(xv.y, wv.y, accP);
            accP = fmaf(xv.z, wv.z, accP);
            accP = fmaf(xv.w, wv.w, accP);
            const int ke = k + 4;
            if (ke == 320 || ke == 640 || ke == 832 || ke == 1024) {
                accT = __fadd_rn(accT, accP); accP = 0.f;
            }
        }
        // top-2 across 64 lanes (lane = expert), lower-index tie-break
        float v1 = accT; int i1 = l;
        float v2 = -INFINITY; int i2 = 1 << 20;
#pragma unroll
        for (int m = 32; m >= 1; m >>= 1) {
            const float ov1 = __shfl_xor(v1, m);
            const int   oi1 = __shfl_xor(i1, m);
            const float ov2 = __shfl_xor(v2, m);
            const int   oi2 = __shfl_xor(i2, m);
            const bool aw = (ov1 > v1) || (ov1 == v1 && oi1 < i1);
            const float nv1 = aw ? ov1 : v1; const int ni1 = aw ? oi1 : i1;
            const float c1v = aw ? v1  : ov1; const int c1i = aw ? i1  : oi1;
            const float c2v = aw ? ov2 : v2;  const int c2i = aw ? oi2 : i2;
            const bool bw = (c1v > c2v) || (c1v == c2v && c1i < c2i);
            v1 = nv1; i1 = ni1;
            v2 = bw ? c1v : c2v; i2 = bw ? c1i : c2i;
        }
        if (l == 0) {
            const float e  = expf(v2 - v1);
            const float dn = 1.0f + e;
            out[t * 2 + 0] = (float)i1;
            out[t * 2 + 1] = (float)i2;
            out[(long)T_TOKENS * 2 + t * 2 + 0] = 1.0f / dn;
            out[(long)T_TOKENS * 2 + t * 2 + 1] = e / dn;
        }
    }
}

extern "C" void kernel_launch(void* const* d_in, const int* in_sizes, int n_in,
                              void* d_out, int out_size, void* d_ws, size_t ws_size,
                              hipStream_t stream) {
    const float* x = (const float*)d_in[0];
    const float* W = (const float*)d_in[1];
    float* out = (float*)d_out;

    unsigned* wcnt = nullptr; unsigned* wlist = nullptr; unsigned cap = 0;
    if (d_ws && ws_size >= 256) {
        wcnt  = (unsigned*)d_ws;
        wlist = wcnt + 16;                       // 64 B header
        size_t c = (ws_size - 64) / 4;
        cap = (unsigned)(c > (1u << 22) ? (1u << 22) : c);
        hipMemsetAsync(d_ws, 0, 64, stream);
    }
    router_mfma<<<dim3(T_TOKENS / 128), dim3(256), 0, stream>>>(x, W, out, wcnt, wlist, cap);
    router_fixup<<<dim3(128), dim3(256), 0, stream>>>(x, W, out, wcnt, wlist, cap);
}